// Round 6
// baseline (416.685 us; speedup 1.0000x reference)
//
#include <hip/hip_runtime.h>
#include <cstdint>
#include <cstddef>

// Problem constants
#define BATCH 8
#define CIN   512
#define COUT  512
#define RES   64
#define HW    4096      // 64*64
#define WDIM  512

typedef short bf16x8 __attribute__((ext_vector_type(8)));
typedef float f32x4  __attribute__((ext_vector_type(4)));
typedef unsigned short ushort8 __attribute__((ext_vector_type(8)));

typedef const __attribute__((address_space(1))) void* gas_ptr;
typedef __attribute__((address_space(3))) void*       las_ptr;

__device__ __forceinline__ unsigned short f2bf(float f) {
    unsigned int u = __float_as_uint(f);
    u += 0x7fffu + ((u >> 16) & 1u);   // round-to-nearest-even
    return (unsigned short)(u >> 16);
}

// ---------------------------------------------------------------------------
// Kernel 1 (fused prep): blocks 0..1023 compute style (+zero zpage);
// blocks 1024..1535 reorganize weights. The two roles are independent.
// style[b][ci] = sum_wd w[b][wd]*affine_w[ci][wd] + affine_b[ci]
// wr[tap][co][ci] = bf16(weight[co][ci][kh][kw]), tap = kh*3+kw
// ---------------------------------------------------------------------------
__global__ __launch_bounds__(256) void prep_kernel(
    const float* __restrict__ w, const float* __restrict__ aw,
    const float* __restrict__ ab, float* __restrict__ style,
    unsigned short* __restrict__ zpage,
    const float* __restrict__ wt, unsigned short* __restrict__ wr)
{
    __shared__ float buf[4608];
    int bid = blockIdx.x;
    int t = threadIdx.x;
    if (bid < 1024) {
        if (bid == 0 && t < 128) zpage[t] = 0;
        int wv = t >> 6, lane = t & 63;
        int idx = bid * 4 + wv;              // 0..4095
        int b = idx >> 9, ci = idx & 511;
        const float* wrow = w + b * WDIM;
        const float* arow = aw + (size_t)ci * WDIM;
        float s = 0.f;
#pragma unroll
        for (int i = 0; i < WDIM / 64; ++i) s += arow[lane + i * 64] * wrow[lane + i * 64];
#pragma unroll
        for (int off = 32; off; off >>= 1) s += __shfl_down(s, off);
        if (lane == 0) style[idx] = s + ab[ci];
    } else {
        int co = bid - 1024;
#pragma unroll
        for (int r = 0; r < 18; ++r) buf[r * 256 + t] = wt[(size_t)co * 4608 + r * 256 + t];
        __syncthreads();
#pragma unroll
        for (int r = 0; r < 18; ++r) {
            int idx = r * 256 + t;
            int tap = idx >> 9, ci = idx & 511;
            wr[(size_t)tap * (COUT * CIN) + co * CIN + ci] = f2bf(buf[ci * 9 + tap]);
        }
    }
}

// ---------------------------------------------------------------------------
// Kernel 2: xs[b][hw][ci] (bf16, NHWC) = bf16(x[b][ci][hw] * style[b][ci])
// 64x64 LDS-tiled transpose; 16B vectorized bf16 stores.
// ---------------------------------------------------------------------------
__global__ __launch_bounds__(256) void modtrans_kernel(
    const float* __restrict__ x, const float* __restrict__ style,
    unsigned short* __restrict__ xs)
{
    __shared__ float tile[64][65];
    int t = threadIdx.x;
    int hw0 = blockIdx.x * 64, ci0 = blockIdx.y * 64, b = blockIdx.z;
    int sub = t >> 6, lane = t & 63;
#pragma unroll
    for (int r = 0; r < 16; ++r) {
        int ci = r * 4 + sub;
        float s = style[b * CIN + ci0 + ci];
        tile[ci][lane] = x[((size_t)(b * CIN + ci0 + ci)) * HW + hw0 + lane] * s;
    }
    __syncthreads();
    int ci8 = (t & 7) * 8;
#pragma unroll
    for (int r = 0; r < 2; ++r) {
        int hw = r * 32 + (t >> 3);
        ushort8 v;
#pragma unroll
        for (int j = 0; j < 8; ++j) v[j] = f2bf(tile[ci8 + j][hw]);
        *(ushort8*)&xs[((size_t)b * HW + hw0 + hw) * CIN + ci0 + ci8] = v;
    }
}

// ---------------------------------------------------------------------------
// Kernel 3: implicit-GEMM conv, 256x256 C-tile, A DIRECT-FROM-GLOBAL
// (NEW this round: weights never touch LDS).
//
// Measured across R1/R3/R5: phase time = DS-read time (288 KB, ~3400 cyc)
// PLUS MFMA time (3725 cyc), additive under every barrier structure - the
// 8 waves convoy (all read, then all MFMA). Register-funded frag double-
// buffering can't fit (acc 128 + base ~124 of 256; R4 spilled).
//
// Fix: A-fragments (2/3 of DS traffic) are read straight from wr to VGPR.
// Each af read is 64 lanes x 16B = 16 rows x 64 B = 16 full cachelines -
// perfectly coalesced global_load_dwordx4, no staging needed. Effects:
//  - DS traffic/phase 288 -> 96 KB (B only): the additive DS term ~gone.
//  - A-feed = per-wave loads with compiler-emitted COUNTED vmcnt waits
//    (vmcnt(7),(6)..., never 0 mid-phase) - AITER's buffer_load<->MFMA
//    pattern, decoupled from barriers; waves desync and L2-hit latency
//    hides under sibling MFMAs. Per-block unique A = 48 KB/phase with
//    4-wave in-block redundancy -> L1/L2 served, L3 backstop (no HBM).
//  - Register delta NEGATIVE: pA[6] gone (-12 VGPR); af frags unchanged.
//  - LDS 132 -> 34 KB (Bs only, double-buffered).
//
// Grid/locality (verified R3): 2cogrp x 16hgrp x 8b = 256 blocks = 1/CU,
// single cohort; bid&7 = b keeps xs[b] (4 MB) L2-resident.
//
// B path unchanged: zero-padded Bs[2][4][66][32], XOR swizzle (verified 0
// conflicts): logical 16B chunk j of LDS row r at physical slot
// j ^ ((r>>1)&3); staging permutes the per-lane GLOBAL source address
// (LDS dest stays base+lane*16); fragment reads apply the same xor.
// Race audit (R3-verified): stage B(p+1) issued after syncthreads(p);
// every wave's Bs^1 reads of phase p-1 were lgkm-drained before it reached
// that barrier -> WAR barrier-separated. Uniform control flow.
// ---------------------------------------------------------------------------
__global__ __launch_bounds__(512, 2) void conv_kernel(
    const unsigned short* __restrict__ xs,   // [8][4096][512] bf16
    const unsigned short* __restrict__ wr,   // [9][512][512]  bf16
    const float* __restrict__ bias,
    const unsigned short* __restrict__ zpage,
    float* __restrict__ y)                   // [8][512][4096] f32
{
    __shared__ __align__(16) unsigned short Bs[2 * 4 * 66 * 32];   // 33 KB
    constexpr int BBUF = 4 * 66 * 32;    // ushorts per B buffer

    const int t   = threadIdx.x;
    const int bid = blockIdx.x;
    // bid&7 = b keeps xs[b] (4 MB) resident in that XCD's L2.
    const int b    = bid & 7;
    const int hgrp = (bid >> 3) & 15;
    const int co0  = (bid >> 7) * 256;
    const int h0   = hgrp * 4;                // 4 image rows per block

    const int lane = t & 63;
    const int wv   = t >> 6;                  // 0..7
    const int wm   = (wv & 1) * 128;          // co offset within tile
    const int wn   = (wv >> 1) * 64;          // hw offset within tile
    const int r16  = lane & 15;
    const int quad = lane >> 4;

    // Per-lane A base offset (in ushorts) within a tap's [512][512] slab:
    // row = co0+wm+r16 (+ mi*16 per fragment), ci chunk = quad*8 (+ ch*32).
    const size_t awoff = (size_t)(co0 + wm + r16) * CIN + quad * 8;

    // zero pad columns (w'=0 and w'=65) of all 4 dh rows in BOTH buffers:
    // 2 buf x 4 dh x 2 cols x 32 = 512 entries, one per thread.
    {
        int bufz = t >> 8;                 // 0 or 1
        int r = t & 255;
        int d = r >> 6, c = r & 63;
        int col = (c < 32) ? 0 : 65;
        Bs[bufz * BBUF + (d * 66 + col) * 32 + (c & 31)] = 0;
    }

    f32x4 acc[8][4];
#pragma unroll
    for (int mi = 0; mi < 8; ++mi)
#pragma unroll
        for (int ni = 0; ni < 4; ++ni)
            acc[mi][ni] = (f32x4){0.f, 0.f, 0.f, 0.f};

    const unsigned short* pB[2];
    int sB[2];

    // (Re)compute B staging pointers for a kh (at its ch=0 position).
    auto setupB = [&](int kh) {
#pragma unroll
        for (int L = 0; L < 2; ++L) {
            int lin = L * 512 + t;                 // 0..1023
            int dh = lin >> 8, r8 = lin & 255;     // dh 0..3
            int wc = r8 >> 2;
            int rowp = dh * 66 + 1 + wc;           // physical LDS row
            int c8 = ((r8 & 3) ^ ((rowp >> 1) & 3)) * 8;
            int hp = h0 + dh + kh - 1;
            bool ok = (unsigned)hp < 64u;
            pB[L] = ok ? xs + ((size_t)b * HW + hp * 64 + wc) * CIN + c8 : zpage;
            sB[L] = ok ? 32 : 0;
        }
    };

    // Issue one phase's 2 B global_load_lds into buffer `buf`; advance ptrs.
    auto stageB = [&](int buf) {
        const int bb = buf * BBUF;
#pragma unroll
        for (int L = 0; L < 2; ++L) {
            int lin = L * 512 + t;
            int dh = lin >> 8, r8 = lin & 255;
            __builtin_amdgcn_global_load_lds((gas_ptr)pB[L],
                (las_ptr)&Bs[bb + (dh * 66 + 1) * 32 + r8 * 8], 16, 0, 0);
            pB[L] += sB[L];
        }
    };

    setupB(0);
    stageB(0);           // prologue: phase 0 B in flight

    for (int p = 0; p < 48; ++p) {
        const int kh = p >> 4;
        const int ci0 = (p & 15) * 32;         // ci chunk offset (ushorts)

        // Drain: B(p) loads complete (and stray A loads of p-1, already
        // consumed); all waves done reading Bs^1 -> safe to overwrite.
        __syncthreads();

        if (p < 47) {
            int pn = p + 1;
            if ((pn & 15) == 0) setupB(pn >> 4);   // kh boundary (pn = 16, 32)
            stageB(pn & 1);                        // flies across compute(p)
        }

        const int bb = (p & 1) * BBUF;
#pragma unroll
        for (int kw = 0; kw < 3; ++kw) {
            const int tap = kh * 3 + kw;
            const unsigned short* pa = wr + (size_t)tap * (COUT * CIN) + awoff + ci0;

            bf16x8 af[8], bfv[4];
            // A: 8 coalesced global->VGPR loads (counted-vmcnt pipelined
            // with the MFMAs below; never barrier-drained mid-phase).
#pragma unroll
            for (int mi = 0; mi < 8; ++mi)
                af[mi] = *(const bf16x8*)(pa + (size_t)mi * 16 * CIN);
            // B: 4 ds_read_b128 from swizzled Bs.
#pragma unroll
            for (int ni = 0; ni < 4; ++ni) {
                int n = wn + ni * 16 + r16;
                int dh = n >> 6, wc = n & 63;
                int row = dh * 66 + wc + kw;
                int ck  = quad ^ ((row >> 1) & 3);
                bfv[ni] = *(const bf16x8*)&Bs[bb + row * 32 + ck * 8];
            }
            __builtin_amdgcn_s_setprio(1);
#pragma unroll
            for (int mi = 0; mi < 8; ++mi)
#pragma unroll
                for (int ni = 0; ni < 4; ++ni)
                    acc[mi][ni] = __builtin_amdgcn_mfma_f32_16x16x32_bf16(
                        af[mi], bfv[ni], acc[mi][ni], 0, 0, 0);
            __builtin_amdgcn_s_setprio(0);
        }
    }

    // Epilogue: C/D layout col(n)=lane&15, row(m)=quad*4+reg
    const size_t hw0 = (size_t)hgrp * 256;
#pragma unroll
    for (int mi = 0; mi < 8; ++mi) {
#pragma unroll
        for (int r = 0; r < 4; ++r) {
            int m = co0 + wm + mi * 16 + quad * 4 + r;
            float bv = bias[m];
            size_t base = ((size_t)b * COUT + m) * HW + hw0;
#pragma unroll
            for (int ni = 0; ni < 4; ++ni) {
                int n = wn + ni * 16 + r16;
                y[base + n] = acc[mi][ni][r] + bv;
            }
        }
    }
}

// ---------------------------------------------------------------------------
extern "C" void kernel_launch(void* const* d_in, const int* in_sizes, int n_in,
                              void* d_out, int out_size, void* d_ws, size_t ws_size,
                              hipStream_t stream)
{
    (void)in_sizes; (void)n_in; (void)out_size; (void)ws_size;
    const float* x    = (const float*)d_in[0];  // [8,512,64,64]
    const float* w    = (const float*)d_in[1];  // [8,512]
    const float* wt   = (const float*)d_in[2];  // [512,512,3,3]
    const float* bias = (const float*)d_in[3];  // [512]
    const float* aw   = (const float*)d_in[4];  // [512,512]
    const float* ab   = (const float*)d_in[5];  // [512]
    float* y = (float*)d_out;                   // [8,512,64,64]

    char* ws = (char*)d_ws;
    float*          style = (float*)ws;                          // 16 KB
    unsigned short* zpage = (unsigned short*)(ws + 16384);       // 256 B
    unsigned short* wr    = (unsigned short*)(ws + 32768);       // 4.5 MB
    unsigned short* xs    = (unsigned short*)(ws + 4751360);     // 32 MB

    prep_kernel<<<1536, 256, 0, stream>>>(w, aw, ab, style, zpage, wt, wr);
    modtrans_kernel<<<dim3(64, 8, 8), 256, 0, stream>>>(x, style, xs);
    conv_kernel<<<256, 512, 0, stream>>>(xs, wr, bias, zpage, y);
}

// Round 7
// 253.156 us; speedup vs baseline: 1.6460x; 1.6460x over previous
//
#include <hip/hip_runtime.h>
#include <cstdint>
#include <cstddef>

// Problem constants
#define BATCH 8
#define CIN   512
#define COUT  512
#define RES   64
#define HW    4096      // 64*64
#define WDIM  512

typedef short bf16x8 __attribute__((ext_vector_type(8)));
typedef float f32x4  __attribute__((ext_vector_type(4)));
typedef unsigned short ushort8 __attribute__((ext_vector_type(8)));

typedef const __attribute__((address_space(1))) void* gas_ptr;
typedef __attribute__((address_space(3))) void*       las_ptr;

__device__ __forceinline__ unsigned short f2bf(float f) {
    unsigned int u = __float_as_uint(f);
    u += 0x7fffu + ((u >> 16) & 1u);   // round-to-nearest-even
    return (unsigned short)(u >> 16);
}

// ---------------------------------------------------------------------------
// Kernel 1 (fused prep): blocks 0..1023 compute style (+zero zpage);
// blocks 1024..1535 reorganize weights. The two roles are independent.
// style[b][ci] = sum_wd w[b][wd]*affine_w[ci][wd] + affine_b[ci]
// wr[tap][co][ci] = bf16(weight[co][ci][kh][kw]), tap = kh*3+kw
// ---------------------------------------------------------------------------
__global__ __launch_bounds__(256) void prep_kernel(
    const float* __restrict__ w, const float* __restrict__ aw,
    const float* __restrict__ ab, float* __restrict__ style,
    unsigned short* __restrict__ zpage,
    const float* __restrict__ wt, unsigned short* __restrict__ wr)
{
    __shared__ float buf[4608];
    int bid = blockIdx.x;
    int t = threadIdx.x;
    if (bid < 1024) {
        if (bid == 0 && t < 128) zpage[t] = 0;
        int wv = t >> 6, lane = t & 63;
        int idx = bid * 4 + wv;              // 0..4095
        int b = idx >> 9, ci = idx & 511;
        const float* wrow = w + b * WDIM;
        const float* arow = aw + (size_t)ci * WDIM;
        float s = 0.f;
#pragma unroll
        for (int i = 0; i < WDIM / 64; ++i) s += arow[lane + i * 64] * wrow[lane + i * 64];
#pragma unroll
        for (int off = 32; off; off >>= 1) s += __shfl_down(s, off);
        if (lane == 0) style[idx] = s + ab[ci];
    } else {
        int co = bid - 1024;
#pragma unroll
        for (int r = 0; r < 18; ++r) buf[r * 256 + t] = wt[(size_t)co * 4608 + r * 256 + t];
        __syncthreads();
#pragma unroll
        for (int r = 0; r < 18; ++r) {
            int idx = r * 256 + t;
            int tap = idx >> 9, ci = idx & 511;
            wr[(size_t)tap * (COUT * CIN) + co * CIN + ci] = f2bf(buf[ci * 9 + tap]);
        }
    }
}

// ---------------------------------------------------------------------------
// Kernel 2: xs[b][hw][ci] (bf16, NHWC) = bf16(x[b][ci][hw] * style[b][ci])
// 64x64 LDS-tiled transpose; 16B vectorized bf16 stores.
// ---------------------------------------------------------------------------
__global__ __launch_bounds__(256) void modtrans_kernel(
    const float* __restrict__ x, const float* __restrict__ style,
    unsigned short* __restrict__ xs)
{
    __shared__ float tile[64][65];
    int t = threadIdx.x;
    int hw0 = blockIdx.x * 64, ci0 = blockIdx.y * 64, b = blockIdx.z;
    int sub = t >> 6, lane = t & 63;
#pragma unroll
    for (int r = 0; r < 16; ++r) {
        int ci = r * 4 + sub;
        float s = style[b * CIN + ci0 + ci];
        tile[ci][lane] = x[((size_t)(b * CIN + ci0 + ci)) * HW + hw0 + lane] * s;
    }
    __syncthreads();
    int ci8 = (t & 7) * 8;
#pragma unroll
    for (int r = 0; r < 2; ++r) {
        int hw = r * 32 + (t >> 3);
        ushort8 v;
#pragma unroll
        for (int j = 0; j < 8; ++j) v[j] = f2bf(tile[ci8 + j][hw]);
        *(ushort8*)&xs[((size_t)b * HW + hw0 + hw) * CIN + ci0 + ci8] = v;
    }
}

// ---------------------------------------------------------------------------
// Kernel 3: implicit-GEMM conv, 256x256 C-tile, m201 8-PHASE-STYLE FINE
// INTERLEAVE (NEW this round): 6 sub-phases per ci-chunk phase, each
//     { 4-8 ds_read_b128 -> s_barrier -> setprio 16-MFMA -> s_barrier }
// (kw x mi-half quadrants). Stage gloads spread 2-at-a-time across
// sub-phases 1..4; ONE vmcnt(0) drain per phase (sub-phase 5), never mid.
//
// Why: per CU-phase MFMA (3725 cyc) and DS (288 KB ~ 3000 cyc) are
// BALANCED, and every coarse schedule measured (R1/R3/R5) gives their SUM
// (7350) - 8 waves convoy. m196->m198 isolated exactly this: coarse
// phase-split ~ 1-phase; 16-MFMA barrier-pair granularity = +28-41% at
// the same occupancy (8 waves, 2/SIMD) and same DS:MFMA balance (m201:
// 62% MfmaUtil). Zero register cost (live frags drop 12 -> 8).
//
// R6 lesson (reverted): A direct-from-global thrashes L2 (wr 4.5 MB +
// xs 4 MB > 4 MB/XCD) -> 2.36 GB to L3, conv 320 us. A stays in LDS.
//
// Race audit: RAW - phase p+1's first ds_read of buf^1 follows
// vmcnt(0)+BAR_A(p,5), so all 8 stage(p+1) gloads are complete
// collectively. WAR - stage(p+1) first issues after BAR_B(p,0) >
// BAR_A(p,0); every wave reaching BAR_A(p,0) finished its phase p-1
// reads of buf^1 (lgkm-drained before its MFMAs). Uniform control flow.
//
// Tile/traffic (verified R3): grid = 2cogrp x 16hgrp x 8b = 256 blocks =
// 1/CU single cohort; bid&7 = b keeps xs[b] (4 MB) L2-resident (FETCH
// 67 MB, HBM 11%). LDS 129 KB double-buffered.
//
// Bank-conflict swizzle (verified 0 conflicts): logical 16B chunk j of
// LDS row r at physical slot j ^ ((r>>1)&3); staging permutes the
// per-lane GLOBAL source address (LDS dest stays base+lane*16); fragment
// reads apply the same xor.
// ---------------------------------------------------------------------------
__global__ __launch_bounds__(512, 2) void conv_kernel(
    const unsigned short* __restrict__ xs,   // [8][4096][512] bf16
    const unsigned short* __restrict__ wr,   // [9][512][512]  bf16
    const float* __restrict__ bias,
    const unsigned short* __restrict__ zpage,
    float* __restrict__ y)                   // [8][512][4096] f32
{
    __shared__ __align__(16) unsigned short As[2 * 3 * 256 * 32];  // 96 KB
    __shared__ __align__(16) unsigned short Bs[2 * 4 * 66 * 32];   // 33 KB
    constexpr int ABUF = 3 * 256 * 32;   // ushorts per A buffer
    constexpr int BBUF = 4 * 66 * 32;    // ushorts per B buffer

    const int t   = threadIdx.x;
    const int bid = blockIdx.x;
    // bid&7 = b keeps xs[b] (4 MB) resident in that XCD's L2.
    const int b    = bid & 7;
    const int hgrp = (bid >> 3) & 15;
    const int co0  = (bid >> 7) * 256;
    const int h0   = hgrp * 4;                // 4 image rows per block

    const int lane = t & 63;
    const int wv   = t >> 6;                  // 0..7
    const int wm   = (wv & 1) * 128;          // co offset within tile
    const int wn   = (wv >> 1) * 64;          // hw offset within tile
    const int r16  = lane & 15;
    const int quad = lane >> 4;

    // zero pad columns (w'=0 and w'=65) of all 4 dh rows in BOTH buffers:
    // 2 buf x 4 dh x 2 cols x 32 = 512 entries, one per thread.
    {
        int bufz = t >> 8;                 // 0 or 1
        int r = t & 255;
        int d = r >> 6, c = r & 63;
        int col = (c < 32) ? 0 : 65;
        Bs[bufz * BBUF + (d * 66 + col) * 32 + (c & 31)] = 0;
    }

    f32x4 acc[8][4];
#pragma unroll
    for (int mi = 0; mi < 8; ++mi)
#pragma unroll
        for (int ni = 0; ni < 4; ++ni)
            acc[mi][ni] = (f32x4){0.f, 0.f, 0.f, 0.f};

    const unsigned short* pA[6];
    const unsigned short* pB[2];
    int sB[2];

    // (Re)compute staging pointers for a kh (at its ch=0 position).
    auto setup = [&](int kh) {
#pragma unroll
        for (int L = 0; L < 6; ++L) {
            int lin = L * 512 + t;                 // 0..3071; phys row = lin>>2
            int tap = kh * 3 + (lin >> 10);        // 3 kw taps
            int q   = (lin >> 2) & 255;            // co row 0..255
            int c8  = ((lin & 3) ^ ((lin >> 3) & 3)) * 8;   // swizzled source chunk
            pA[L] = wr + (size_t)tap * (COUT * CIN) + (co0 + q) * CIN + c8;
        }
#pragma unroll
        for (int L = 0; L < 2; ++L) {
            int lin = L * 512 + t;                 // 0..1023
            int dh = lin >> 8, r8 = lin & 255;     // dh 0..3
            int wc = r8 >> 2;
            int rowp = dh * 66 + 1 + wc;           // physical LDS row
            int c8 = ((r8 & 3) ^ ((rowp >> 1) & 3)) * 8;
            int hp = h0 + dh + kh - 1;
            bool ok = (unsigned)hp < 64u;
            pB[L] = ok ? xs + ((size_t)b * HW + hp * 64 + wc) * CIN + c8 : zpage;
            sB[L] = ok ? 32 : 0;
        }
    };

    // Issue 2 of the 6 A gloads (L = i0, i0+1) into buffer `buf`.
    auto stageA2 = [&](int buf, int i0) {
        const int ab2 = buf * ABUF;
#pragma unroll
        for (int k = 0; k < 2; ++k) {
            int L = i0 + k;
            int lin = L * 512 + t;
            __builtin_amdgcn_global_load_lds((gas_ptr)pA[L], (las_ptr)&As[ab2 + lin * 8], 16, 0, 0);
            pA[L] += 32;
        }
    };
    // Issue the 2 B gloads into buffer `buf`.
    auto stageB2 = [&](int buf) {
        const int bb2 = buf * BBUF;
#pragma unroll
        for (int L = 0; L < 2; ++L) {
            int lin = L * 512 + t;
            int dh = lin >> 8, r8 = lin & 255;
            __builtin_amdgcn_global_load_lds((gas_ptr)pB[L],
                (las_ptr)&Bs[bb2 + (dh * 66 + 1) * 32 + r8 * 8], 16, 0, 0);
            pB[L] += sB[L];
        }
    };

    // Read 4 A fragments (one mi-half of one kw) / 4 B fragments (one kw).
    auto load_a = [&](int ab, int kw, int half, bf16x8* af) {
#pragma unroll
        for (int mi = 0; mi < 4; ++mi) {
            int row = kw * 256 + wm + (half * 4 + mi) * 16 + r16;
            int ck  = quad ^ ((row >> 1) & 3);
            af[mi] = *(const bf16x8*)&As[ab + row * 32 + ck * 8];
        }
    };
    auto load_b = [&](int bb, int kw, bf16x8* bfv) {
#pragma unroll
        for (int ni = 0; ni < 4; ++ni) {
            int n = wn + ni * 16 + r16;
            int dh = n >> 6, wc = n & 63;
            int row = dh * 66 + wc + kw;
            int ck  = quad ^ ((row >> 1) & 3);
            bfv[ni] = *(const bf16x8*)&Bs[bb + row * 32 + ck * 8];
        }
    };
    // One 16-MFMA quadrant cluster (mi-half x all ni), setprio-wrapped.
    auto mfma16 = [&](const bf16x8* af, const bf16x8* bfv, int half) {
        __builtin_amdgcn_s_setprio(1);
#pragma unroll
        for (int mi = 0; mi < 4; ++mi)
#pragma unroll
            for (int ni = 0; ni < 4; ++ni)
                acc[half * 4 + mi][ni] = __builtin_amdgcn_mfma_f32_16x16x32_bf16(
                    af[mi], bfv[ni], acc[half * 4 + mi][ni], 0, 0, 0);
        __builtin_amdgcn_s_setprio(0);
    };

    setup(0);
    stageA2(0, 0); stageA2(0, 2); stageA2(0, 4); stageB2(0);   // phase 0
    __syncthreads();     // full drain once: buf0 valid, pad zeros visible

    for (int p = 0; p < 48; ++p) {
        const int ab = (p & 1) * ABUF, bb = (p & 1) * BBUF;
        const int pn = p + 1;
        const bool st = (p < 47);
        const int nb = pn & 1;
        bf16x8 afA[4], afB[4], bfv[4];

        // --- s0: kw0/half0 ---
        load_a(ab, 0, 0, afA); load_b(bb, 0, bfv);
        __builtin_amdgcn_s_barrier();
        mfma16(afA, bfv, 0);
        __builtin_amdgcn_s_barrier();

        if (st && (pn & 15) == 0) setup(pn >> 4);   // kh boundary (pn=16,32)

        // --- s1: kw0/half1 | stage A[0:2] ---
        load_a(ab, 0, 1, afB);
        if (st) stageA2(nb, 0);
        __builtin_amdgcn_s_barrier();
        mfma16(afB, bfv, 1);
        __builtin_amdgcn_s_barrier();

        // --- s2: kw1/half0 | stage A[2:4] ---
        load_a(ab, 1, 0, afA); load_b(bb, 1, bfv);
        if (st) stageA2(nb, 2);
        __builtin_amdgcn_s_barrier();
        mfma16(afA, bfv, 0);
        __builtin_amdgcn_s_barrier();

        // --- s3: kw1/half1 | stage A[4:6] ---
        load_a(ab, 1, 1, afB);
        if (st) stageA2(nb, 4);
        __builtin_amdgcn_s_barrier();
        mfma16(afB, bfv, 1);
        __builtin_amdgcn_s_barrier();

        // --- s4: kw2/half0 | stage B ---
        load_a(ab, 2, 0, afA); load_b(bb, 2, bfv);
        if (st) stageB2(nb);
        __builtin_amdgcn_s_barrier();
        mfma16(afA, bfv, 0);
        __builtin_amdgcn_s_barrier();

        // --- s5: kw2/half1 | single per-phase vmcnt drain ---
        load_a(ab, 2, 1, afB);
        asm volatile("s_waitcnt vmcnt(0)" ::: "memory");
        __builtin_amdgcn_s_barrier();
        mfma16(afB, bfv, 1);
        __builtin_amdgcn_s_barrier();
    }

    // Epilogue: C/D layout col(n)=lane&15, row(m)=quad*4+reg
    const size_t hw0 = (size_t)hgrp * 256;
#pragma unroll
    for (int mi = 0; mi < 8; ++mi) {
#pragma unroll
        for (int r = 0; r < 4; ++r) {
            int m = co0 + wm + mi * 16 + quad * 4 + r;
            float bv = bias[m];
            size_t base = ((size_t)b * COUT + m) * HW + hw0;
#pragma unroll
            for (int ni = 0; ni < 4; ++ni) {
                int n = wn + ni * 16 + r16;
                y[base + n] = acc[mi][ni][r] + bv;
            }
        }
    }
}

// ---------------------------------------------------------------------------
extern "C" void kernel_launch(void* const* d_in, const int* in_sizes, int n_in,
                              void* d_out, int out_size, void* d_ws, size_t ws_size,
                              hipStream_t stream)
{
    (void)in_sizes; (void)n_in; (void)out_size; (void)ws_size;
    const float* x    = (const float*)d_in[0];  // [8,512,64,64]
    const float* w    = (const float*)d_in[1];  // [8,512]
    const float* wt   = (const float*)d_in[2];  // [512,512,3,3]
    const float* bias = (const float*)d_in[3];  // [512]
    const float* aw   = (const float*)d_in[4];  // [512,512]
    const float* ab   = (const float*)d_in[5];  // [512]
    float* y = (float*)d_out;                   // [8,512,64,64]

    char* ws = (char*)d_ws;
    float*          style = (float*)ws;                          // 16 KB
    unsigned short* zpage = (unsigned short*)(ws + 16384);       // 256 B
    unsigned short* wr    = (unsigned short*)(ws + 32768);       // 4.5 MB
    unsigned short* xs    = (unsigned short*)(ws + 4751360);     // 32 MB

    prep_kernel<<<1536, 256, 0, stream>>>(w, aw, ab, style, zpage, wt, wr);
    modtrans_kernel<<<dim3(64, 8, 8), 256, 0, stream>>>(x, style, xs);
    conv_kernel<<<256, 512, 0, stream>>>(xs, wr, bias, zpage, y);
}